// Round 1
// baseline (343.156 us; speedup 1.0000x reference)
//
#include <hip/hip_runtime.h>

// Problem constants
#define B_SZ   64
#define C_SZ   3
#define IMG_SZ 512
#define PS_SZ  16
#define G_SZ   32
#define P2_SZ  256    // PS*PS
// Grouped GEMM view: per (c,g): M = B*32 = 2048 rows, K = 256, N = 256

#define BM 128
#define BN 128
#define BK 16
#define TM 8
#define TN 8
// threads = (BM/TM)*(BN/TN) = 16*16 = 256

__global__ __launch_bounds__(256, 2)
void obf_gemm_kernel(const float* __restrict__ x,
                     const float* __restrict__ w,
                     const float* __restrict__ bias,
                     const int* __restrict__ perm,
                     float* __restrict__ out)
{
    const int mtile = blockIdx.x;     // 0..15   (M = 2048 / BM)
    const int ntile = blockIdx.y;     // 0..1    (N = 256 / BN)
    const int cg    = blockIdx.z;     // 0..95
    const int c = cg >> 5;            // input/computed channel
    const int g = cg & 31;            // patch group

    const int tid = threadIdx.x;
    const int tx  = tid & 15;         // output-col group
    const int ty  = tid >> 4;         // output-row group

    // A stored transposed: As[k][m]; pad +4 keeps float4 alignment (132*4 % 16 == 0)
    __shared__ float As[BK][BM + 4];
    __shared__ float Bs[BK][BN];

    float acc[TM][TN];
    #pragma unroll
    for (int i = 0; i < TM; ++i)
        #pragma unroll
        for (int j = 0; j < TN; ++j) acc[i][j] = 0.f;

    // inverse channel permutation: computed channel c -> output channel cp
    int cp = 0;
    #pragma unroll
    for (int i = 0; i < C_SZ; ++i) if (perm[i] == c) cp = i;

    const float* wbase = w + ((size_t)(c * G_SZ + g)) * P2_SZ * P2_SZ + ntile * BN;

    for (int ks = 0; ks < P2_SZ / BK; ++ks) {   // 16 K-steps; ks == patch row r
        // ---- stage A: 128 rows x 16 k (each row's k-slice is 16 contiguous floats) ----
        #pragma unroll
        for (int pass = 0; pass < 2; ++pass) {
            const int q  = tid + 256 * pass;    // 512 float4 chunks
            const int m  = q >> 2;              // tile row 0..127
            const int kc = (q & 3) * 4;         // k offset within BK
            const int mg = mtile * BM + m;      // global M row
            const int b  = mg >> 5;             // batch
            const int nh = mg & 31;             // patch row index
            const int nw = (g - nh) & 31;       // patch col index: (nh+nw)%32 == g
            const float4 v = *reinterpret_cast<const float4*>(
                x + (((size_t)(b * C_SZ + c) * IMG_SZ + nh * PS_SZ + ks) * IMG_SZ
                     + nw * PS_SZ + kc));
            As[kc + 0][m] = v.x;
            As[kc + 1][m] = v.y;
            As[kc + 2][m] = v.z;
            As[kc + 3][m] = v.w;
        }
        // ---- stage B (weights): 16 k-rows x 128 cols, fully coalesced ----
        #pragma unroll
        for (int pass = 0; pass < 2; ++pass) {
            const int q   = tid + 256 * pass;   // 512 float4 chunks
            const int kk  = q >> 5;             // 0..15
            const int col = (q & 31) * 4;       // 0..124
            *reinterpret_cast<float4*>(&Bs[kk][col]) =
                *reinterpret_cast<const float4*>(
                    wbase + (size_t)(ks * BK + kk) * P2_SZ + col);
        }
        __syncthreads();

        #pragma unroll
        for (int kk = 0; kk < BK; ++kk) {
            const float4 a0 = *reinterpret_cast<const float4*>(&As[kk][ty * TM]);
            const float4 a1 = *reinterpret_cast<const float4*>(&As[kk][ty * TM + 4]);
            const float4 b0 = *reinterpret_cast<const float4*>(&Bs[kk][tx * TN]);
            const float4 b1 = *reinterpret_cast<const float4*>(&Bs[kk][tx * TN + 4]);
            const float a[TM]  = {a0.x, a0.y, a0.z, a0.w, a1.x, a1.y, a1.z, a1.w};
            const float bb[TN] = {b0.x, b0.y, b0.z, b0.w, b1.x, b1.y, b1.z, b1.w};
            #pragma unroll
            for (int i = 0; i < TM; ++i)
                #pragma unroll
                for (int j = 0; j < TN; ++j)
                    acc[i][j] = fmaf(a[i], bb[j], acc[i][j]);
        }
        __syncthreads();
    }

    // ---- epilogue: bias + tanh + un-patch + channel permute ----
    const int o_base = ntile * BN + tx * TN;     // multiple of 8 -> single image row seg
    const int r_out  = o_base >> 4;              // patch-local row
    const int cc_out = o_base & 15;              // patch-local col (0 or 8)
    const float* bp = bias + (size_t)(c * G_SZ + g) * P2_SZ + o_base;
    float bv[TN];
    #pragma unroll
    for (int j = 0; j < TN; ++j) bv[j] = bp[j];

    #pragma unroll
    for (int i = 0; i < TM; ++i) {
        const int mg = mtile * BM + ty * TM + i;
        const int b  = mg >> 5;
        const int nh = mg & 31;
        const int nw = (g - nh) & 31;
        float* optr = out + (((size_t)(b * C_SZ + cp) * IMG_SZ + nh * PS_SZ + r_out)
                             * IMG_SZ + nw * PS_SZ + cc_out);
        float4 v0, v1;
        v0.x = tanhf(acc[i][0] + bv[0]);
        v0.y = tanhf(acc[i][1] + bv[1]);
        v0.z = tanhf(acc[i][2] + bv[2]);
        v0.w = tanhf(acc[i][3] + bv[3]);
        v1.x = tanhf(acc[i][4] + bv[4]);
        v1.y = tanhf(acc[i][5] + bv[5]);
        v1.z = tanhf(acc[i][6] + bv[6]);
        v1.w = tanhf(acc[i][7] + bv[7]);
        *reinterpret_cast<float4*>(optr)     = v0;
        *reinterpret_cast<float4*>(optr + 4) = v1;
    }
}

extern "C" void kernel_launch(void* const* d_in, const int* in_sizes, int n_in,
                              void* d_out, int out_size, void* d_ws, size_t ws_size,
                              hipStream_t stream) {
    const float* x    = (const float*)d_in[0];
    const float* w    = (const float*)d_in[1];
    const float* bias = (const float*)d_in[2];
    const int*   perm = (const int*)d_in[3];
    float* out = (float*)d_out;

    dim3 grid(2048 / BM, P2_SZ / BN, C_SZ * G_SZ);   // (16, 2, 96)
    obf_gemm_kernel<<<grid, 256, 0, stream>>>(x, w, bias, perm, out);
}

// Round 2
// 150.280 us; speedup vs baseline: 2.2835x; 2.2835x over previous
//
#include <hip/hip_runtime.h>

// ---- problem constants ----
#define C_SZ   3
#define IMG_SZ 512
#define G_SZ   32
#define P2_SZ  256
// per (c,g) GEMM: M = 64*32 = 2048, K = 256, N = 256

typedef short  short8 __attribute__((ext_vector_type(8)));   // 8 bf16 (4 VGPR)
typedef float  f32x4  __attribute__((ext_vector_type(4)));
typedef unsigned short u16;
typedef u16    u16x8  __attribute__((ext_vector_type(8)));

__device__ __forceinline__ u16 f2bf(float f) {
    unsigned u = __float_as_uint(f);
    u += 0x7FFFu + ((u >> 16) & 1u);          // round-to-nearest-even
    return (u16)(u >> 16);
}

__device__ __forceinline__ float tanh_fast(float v) {
    float e = __expf(2.f * v);                // v_exp_f32 path
    return 1.f - 2.f * __builtin_amdgcn_rcpf(e + 1.f);
}

// ---------- prep: wt[c][g][o][p] (bf16) = w[c][g][p][o] ----------
__global__ __launch_bounds__(256)
void prep_wt(const float* __restrict__ w, u16* __restrict__ wt) {
    const int cg = blockIdx.x;        // 0..95
    const int pt = blockIdx.y;        // p tile 0..3
    const int ot = blockIdx.z;        // o tile 0..3
    __shared__ float T[64][68];
    const int tid = threadIdx.x;
    const float* wb = w + (size_t)cg * 65536 + (size_t)(pt * 64) * 256 + ot * 64;
    #pragma unroll
    for (int pass = 0; pass < 4; ++pass) {
        int q  = pass * 256 + tid;
        int pl = q >> 4, o4 = (q & 15) * 4;
        float4 v = *reinterpret_cast<const float4*>(wb + (size_t)pl * 256 + o4);
        T[pl][o4 + 0] = v.x; T[pl][o4 + 1] = v.y;
        T[pl][o4 + 2] = v.z; T[pl][o4 + 3] = v.w;
    }
    __syncthreads();
    const int pch = tid & 3, ol = tid >> 2;   // 4 p-chunks x 64 o
    u16x8 v0, v1;
    #pragma unroll
    for (int j = 0; j < 8; ++j)  v0[j] = f2bf(T[pch * 16 + j][ol]);
    #pragma unroll
    for (int j = 0; j < 8; ++j)  v1[j] = f2bf(T[pch * 16 + 8 + j][ol]);
    u16* dst = wt + (size_t)cg * 65536 + (size_t)(ot * 64 + ol) * 256 + pt * 64 + pch * 16;
    *reinterpret_cast<u16x8*>(dst)     = v0;
    *reinterpret_cast<u16x8*>(dst + 8) = v1;
}

// ---------- main GEMM: BM=64 x BN=256, BK=32, 4 waves (each 64x64) ----------
__global__ __launch_bounds__(256, 2)
void obf_mfma(const float* __restrict__ x,
              const u16*  __restrict__ wt,
              const float* __restrict__ bias,
              const int*  __restrict__ perm,
              float* __restrict__ out)
{
    const int mtile = blockIdx.x;     // 0..31
    const int cg    = blockIdx.z;     // 0..95
    const int c = cg >> 5, g = cg & 31;
    const int tid  = threadIdx.x;
    const int lane = tid & 63, wv = tid >> 6;

    __shared__ u16 As[64][40];        // [m][k], pad->80B rows (16B-aligned, 2-way banks)
    __shared__ u16 Bs[256][40];       // [n][k]

    f32x4 acc[4][4] = {};

    int cp = 0;
    #pragma unroll
    for (int i = 0; i < C_SZ; ++i) if (perm[i] == c) cp = i;

    // ---- hoisted staging addresses ----
    // A: q = pass*256+tid -> ml = q>>3, half = (q>>2)&1, f4 = q&3
    const float* a_src[2];
    int a_ml[2], a_half[2], a_f4[2];
    #pragma unroll
    for (int pass = 0; pass < 2; ++pass) {
        int q    = pass * 256 + tid;
        int ml   = q >> 3, half = (q >> 2) & 1, f4 = q & 3;
        int mg   = mtile * 64 + ml;
        int b    = mg >> 5, nh = mg & 31, nw = (g - nh) & 31;
        a_src[pass] = x + (((size_t)(b * C_SZ + c) * IMG_SZ + nh * 16 + half) * IMG_SZ
                           + nw * 16 + f4 * 4);
        a_ml[pass] = ml; a_half[pass] = half; a_f4[pass] = f4;
    }
    // B: q = pass*256+tid -> n = q>>2, ch = q&3
    const u16* b_src[4];
    int b_n[4], b_ch[4];
    const u16* wtb = wt + (size_t)cg * 65536;
    #pragma unroll
    for (int pass = 0; pass < 4; ++pass) {
        int q = pass * 256 + tid;
        b_n[pass] = q >> 2; b_ch[pass] = q & 3;
        b_src[pass] = wtb + (size_t)b_n[pass] * 256 + b_ch[pass] * 8;
    }

    for (int ks = 0; ks < 8; ++ks) {
        // ---- stage A (fp32 -> bf16) ----
        #pragma unroll
        for (int pass = 0; pass < 2; ++pass) {
            float4 v = *reinterpret_cast<const float4*>(a_src[pass] + (size_t)ks * 2 * IMG_SZ);
            u16* d = &As[a_ml[pass]][a_half[pass] * 16 + a_f4[pass] * 4];
            d[0] = f2bf(v.x); d[1] = f2bf(v.y); d[2] = f2bf(v.z); d[3] = f2bf(v.w);
        }
        // ---- stage B (bf16 passthrough, 16B chunks) ----
        #pragma unroll
        for (int pass = 0; pass < 4; ++pass) {
            uint4 v = *reinterpret_cast<const uint4*>(b_src[pass] + ks * 32);
            *reinterpret_cast<uint4*>(&Bs[b_n[pass]][b_ch[pass] * 8]) = v;
        }
        __syncthreads();

        short8 a[4], b[4];
        const int r = lane & 15, koff = (lane >> 4) * 8;
        #pragma unroll
        for (int mi = 0; mi < 4; ++mi)
            a[mi] = *reinterpret_cast<const short8*>(&As[mi * 16 + r][koff]);
        #pragma unroll
        for (int ni = 0; ni < 4; ++ni)
            b[ni] = *reinterpret_cast<const short8*>(&Bs[wv * 64 + ni * 16 + r][koff]);
        #pragma unroll
        for (int mi = 0; mi < 4; ++mi)
            #pragma unroll
            for (int ni = 0; ni < 4; ++ni)
                acc[mi][ni] = __builtin_amdgcn_mfma_f32_16x16x32_bf16(
                    a[mi], b[ni], acc[mi][ni], 0, 0, 0);
        __syncthreads();
    }

    // ---- epilogue: bias + tanh + un-patch + channel permute ----
    const int cc = lane & 15;               // patch-local col == output col low bits
    float bv[4];
    #pragma unroll
    for (int ni = 0; ni < 4; ++ni)
        bv[ni] = bias[(size_t)cg * 256 + wv * 64 + ni * 16 + cc];

    #pragma unroll
    for (int mi = 0; mi < 4; ++mi) {
        #pragma unroll
        for (int reg = 0; reg < 4; ++reg) {
            const int ml = mi * 16 + (lane >> 4) * 4 + reg;
            const int mg = mtile * 64 + ml;
            const int b  = mg >> 5, nh = mg & 31, nw = (g - nh) & 31;
            float* orow = out + ((size_t)(b * C_SZ + cp) * IMG_SZ + nh * 16) * IMG_SZ
                              + nw * 16 + cc;
            #pragma unroll
            for (int ni = 0; ni < 4; ++ni) {
                const int rp = wv * 4 + ni;          // patch-local row
                orow[(size_t)rp * IMG_SZ] = tanh_fast(acc[mi][ni][reg] + bv[ni]);
            }
        }
    }
}

extern "C" void kernel_launch(void* const* d_in, const int* in_sizes, int n_in,
                              void* d_out, int out_size, void* d_ws, size_t ws_size,
                              hipStream_t stream) {
    const float* x    = (const float*)d_in[0];
    const float* w    = (const float*)d_in[1];
    const float* bias = (const float*)d_in[2];
    const int*   perm = (const int*)d_in[3];
    float* out = (float*)d_out;
    u16*   wt  = (u16*)d_ws;          // needs 96*65536*2 = 12.6 MB of scratch

    dim3 pgrid(C_SZ * G_SZ, 4, 4);    // (96,4,4)
    prep_wt<<<pgrid, 256, 0, stream>>>(w, wt);

    dim3 grid(32, 1, C_SZ * G_SZ);    // (32,1,96)
    obf_mfma<<<grid, 256, 0, stream>>>(x, wt, bias, perm, out);
}

// Round 3
// 149.837 us; speedup vs baseline: 2.2902x; 1.0030x over previous
//
#include <hip/hip_runtime.h>

// ---- problem constants ----
#define C_SZ   3
#define IMG_SZ 512
#define G_SZ   32
// per (c,g) GEMM: M = 64*32 = 2048, K = 256, N = 256

typedef short  short8 __attribute__((ext_vector_type(8)));   // 8 bf16 (4 VGPR)
typedef float  f32x4  __attribute__((ext_vector_type(4)));
typedef unsigned short u16;
typedef u16    u16x8  __attribute__((ext_vector_type(8)));

__device__ __forceinline__ u16 f2bf(float f) {
    unsigned u = __float_as_uint(f);
    u += 0x7FFFu + ((u >> 16) & 1u);          // round-to-nearest-even
    return (u16)(u >> 16);
}

__device__ __forceinline__ float tanh_fast(float v) {
    float e = __expf(2.f * v);
    return 1.f - 2.f * __builtin_amdgcn_rcpf(e + 1.f);
}

// ---------- prep: wt3[cg][kb][kg][n][e] = bf16(w[cg][kb*32+kg*8+e][n]) ----------
// Fragment-ordered: lane (kg = lane>>4, r = lane&15) reads its 16B MFMA B-operand
// for (ks=kb, n = nbase+r) at a single contiguous address.
__global__ __launch_bounds__(256)
void prep_wt(const float* __restrict__ w, u16* __restrict__ wt) {
    const int cg = blockIdx.x;        // 0..95
    const int kb = blockIdx.y;        // 0..7
    __shared__ float T[32][260];      // +4 pad: conflict-free column gather
    const int tid = threadIdx.x;
    const float* wb = w + (size_t)cg * 65536 + (size_t)kb * 32 * 256;
    #pragma unroll
    for (int pass = 0; pass < 8; ++pass) {
        int q = pass * 256 + tid;     // 2048 float4 chunks
        int pl = q >> 6, o4 = (q & 63) * 4;
        float4 v = *reinterpret_cast<const float4*>(wb + (size_t)pl * 256 + o4);
        T[pl][o4 + 0] = v.x; T[pl][o4 + 1] = v.y;
        T[pl][o4 + 2] = v.z; T[pl][o4 + 3] = v.w;
    }
    __syncthreads();
    u16* dst = wt + ((size_t)cg * 8 + kb) * 8192;
    #pragma unroll
    for (int h0 = 0; h0 < 4; ++h0) {
        int h = h0 * 256 + tid;       // kg x n chunks, stores fully coalesced
        int kg = h >> 8, n = h & 255;
        u16x8 v;
        #pragma unroll
        for (int e = 0; e < 8; ++e) v[e] = f2bf(T[kg * 8 + e][n]);
        *reinterpret_cast<u16x8*>(dst + (size_t)kg * 2048 + n * 8) = v;
    }
}

// ---------- main GEMM: BM=64 x BN=256, BK=32, 4 waves (each 64x64) ----------
// A double-buffered in LDS (shared by all waves); B direct global->reg fragments.
__global__ __launch_bounds__(256, 3)
void obf_mfma(const float* __restrict__ x,
              const u16*  __restrict__ wt,
              const float* __restrict__ bias,
              const int*  __restrict__ perm,
              float* __restrict__ out)
{
    // bijective XCD swizzle: 3072 blocks = 8 XCDs x 384; same-cg blocks share an XCD
    const int bid  = blockIdx.x;
    const int sbid = (bid & 7) * 384 + (bid >> 3);
    const int mtile = sbid & 31;      // 0..31
    const int cg    = sbid >> 5;      // 0..95
    const int c = cg >> 5, g = cg & 31;
    const int tid  = threadIdx.x;
    const int lane = tid & 63, wv = tid >> 6;

    __shared__ u16 As[2][64][40];     // [buf][m][k], 80B rows (2-way banks = free)

    f32x4 acc[4][4] = {};

    int cp = 0;
    #pragma unroll
    for (int i = 0; i < C_SZ; ++i) if (perm[i] == c) cp = i;

    // ---- A staging addresses (2 float4 chunks per thread per K-step) ----
    const float* a_src[2];
    int a_off[2];
    #pragma unroll
    for (int pass = 0; pass < 2; ++pass) {
        int q    = pass * 256 + tid;
        int ml   = q >> 3, half = (q >> 2) & 1, f4 = q & 3;
        int mg   = mtile * 64 + ml;
        int b    = mg >> 5, nh = mg & 31, nw = (g - nh) & 31;
        a_src[pass] = x + (((size_t)(b * C_SZ + c) * IMG_SZ + nh * 16 + half) * IMG_SZ
                           + nw * 16 + f4 * 4);
        a_off[pass] = ml * 40 + half * 16 + f4 * 4;
    }
    // ---- B fragment base: lane-contiguous 16B loads ----
    const int r = lane & 15, kg = lane >> 4;
    const u16* bsrc = wt + (size_t)cg * 65536 + kg * 2048 + ((size_t)(wv * 64 + r)) * 8;

    // ---- prologue: stage step 0 ----
    f32x4 av[2];
    av[0] = *reinterpret_cast<const f32x4*>(a_src[0]);
    av[1] = *reinterpret_cast<const f32x4*>(a_src[1]);
    short8 bfrag[4];
    #pragma unroll
    for (int ni = 0; ni < 4; ++ni)
        bfrag[ni] = *reinterpret_cast<const short8*>(bsrc + ni * 128);
    #pragma unroll
    for (int pass = 0; pass < 2; ++pass) {
        u16* d = &As[0][0][0] + a_off[pass];
        d[0] = f2bf(av[pass][0]); d[1] = f2bf(av[pass][1]);
        d[2] = f2bf(av[pass][2]); d[3] = f2bf(av[pass][3]);
    }
    __syncthreads();

    const int koff = kg * 8;
    #pragma unroll
    for (int ks = 0; ks < 8; ++ks) {
        // issue next step's global loads early (hide HBM/L2 latency under MFMA)
        f32x4 an[2];
        short8 bn[4];
        if (ks < 7) {
            an[0] = *reinterpret_cast<const f32x4*>(a_src[0] + (size_t)(ks + 1) * 2 * IMG_SZ);
            an[1] = *reinterpret_cast<const f32x4*>(a_src[1] + (size_t)(ks + 1) * 2 * IMG_SZ);
            #pragma unroll
            for (int ni = 0; ni < 4; ++ni)
                bn[ni] = *reinterpret_cast<const short8*>(bsrc + (ks + 1) * 8192 + ni * 128);
        }
        // compute current step from LDS buf ks&1
        const u16* abase = &As[ks & 1][0][0];
        short8 a[4];
        #pragma unroll
        for (int mi = 0; mi < 4; ++mi)
            a[mi] = *reinterpret_cast<const short8*>(abase + (mi * 16 + r) * 40 + koff);
        #pragma unroll
        for (int mi = 0; mi < 4; ++mi)
            #pragma unroll
            for (int ni = 0; ni < 4; ++ni)
                acc[mi][ni] = __builtin_amdgcn_mfma_f32_16x16x32_bf16(
                    a[mi], bfrag[ni], acc[mi][ni], 0, 0, 0);
        // write-late: convert + stage next step into the other buffer
        if (ks < 7) {
            u16* d0 = &As[(ks & 1) ^ 1][0][0];
            #pragma unroll
            for (int pass = 0; pass < 2; ++pass) {
                u16* d = d0 + a_off[pass];
                d[0] = f2bf(an[pass][0]); d[1] = f2bf(an[pass][1]);
                d[2] = f2bf(an[pass][2]); d[3] = f2bf(an[pass][3]);
            }
            #pragma unroll
            for (int ni = 0; ni < 4; ++ni) bfrag[ni] = bn[ni];
        }
        __syncthreads();
    }

    // ---- epilogue: bias + tanh + un-patch + channel permute ----
    const int cc = lane & 15;
    float bs[4];
    #pragma unroll
    for (int ni = 0; ni < 4; ++ni)
        bs[ni] = bias[(size_t)cg * 256 + wv * 64 + ni * 16 + cc];

    #pragma unroll
    for (int mi = 0; mi < 4; ++mi) {
        #pragma unroll
        for (int reg = 0; reg < 4; ++reg) {
            const int ml = mi * 16 + (lane >> 4) * 4 + reg;
            const int mg = mtile * 64 + ml;
            const int b  = mg >> 5, nh = mg & 31, nw = (g - nh) & 31;
            float* orow = out + ((size_t)(b * C_SZ + cp) * IMG_SZ + nh * 16) * IMG_SZ
                              + nw * 16 + cc;
            #pragma unroll
            for (int ni = 0; ni < 4; ++ni) {
                const int rp = wv * 4 + ni;          // patch-local row
                orow[(size_t)rp * IMG_SZ] = tanh_fast(acc[mi][ni][reg] + bs[ni]);
            }
        }
    }
}

extern "C" void kernel_launch(void* const* d_in, const int* in_sizes, int n_in,
                              void* d_out, int out_size, void* d_ws, size_t ws_size,
                              hipStream_t stream) {
    const float* x    = (const float*)d_in[0];
    const float* w    = (const float*)d_in[1];
    const float* bias = (const float*)d_in[2];
    const int*   perm = (const int*)d_in[3];
    float* out = (float*)d_out;
    u16*   wt  = (u16*)d_ws;          // 96*65536*2 = 12.6 MB scratch

    dim3 pgrid(C_SZ * G_SZ, 8, 1);    // (96,8)
    prep_wt<<<pgrid, 256, 0, stream>>>(w, wt);

    obf_mfma<<<3072, 256, 0, stream>>>(x, wt, bias, perm, out);
}